// Round 2
// baseline (147.277 us; speedup 1.0000x reference)
//
#include <hip/hip_runtime.h>
#include <cstdint>
#include <cstddef>

#define BS      64
#define NPRED   25200
#define KTOP    512
#define MAXDET  300
#define NBINS   4096
#define CAP     1024
#define NTHR    1024
#define CONF_T  0.25f
#define IOU_T   0.45f
#define MAXWH   7680.0f

// Single fused kernel: one block per image. NO d_ws usage (R1 post-timing
// divergence was traced to OOB writes past ws_size corrupting neighboring
// allocations — this kernel touches only pred (read) and out (write)).
__global__ __launch_bounds__(NTHR) void yolo_k(const float* __restrict__ pred,
                                               float* __restrict__ out) {
  // ---- overlaid LDS: phase-1 (score cache + histogram) vs phase-2 (boxes+mask)
  __shared__ __align__(16) unsigned char smem[121280];
  __shared__ float sv[CAP];              // persistent: sorted scores (topv)
  __shared__ int   si[CAP];              // persistent: sorted indices (topi)
  __shared__ unsigned int supW[16];
  __shared__ int cutoff_s, cnt_s;

  // phase-1 views (dead after phase B)
  float*        scoreL = (float*)smem;                    // 25200 f32 = 100800 B
  unsigned int* hist   = (unsigned int*)(smem + 100800);  // 4096 u32  = 16384 B
  unsigned int* gsum   = (unsigned int*)(smem + 117184);  // 1024 u32  = 4096 B
  // phase-2 views (written from phase D on; same bytes)
  float* bx0 = (float*)(smem);            // un-offset xyxy (transposed)
  float* bx1 = (float*)(smem + 2048);
  float* bx2 = (float*)(smem + 4096);
  float* bx3 = (float*)(smem + 6144);
  float* ox0 = (float*)(smem + 8192);     // class-offset xyxy (transposed)
  float* oy0 = (float*)(smem + 10240);
  float* ox1 = (float*)(smem + 12288);
  float* oy1 = (float*)(smem + 14336);
  float* areaL = (float*)(smem + 16384);
  int*   cidL  = (int*)(smem + 18432);
  unsigned int* mask = (unsigned int*)(smem + 20480);     // 512*17 u32 = 34816 B
  int*   scanb = (int*)(smem + 55296);                    // 512 i32

  const int tid = threadIdx.x;
  const int img = blockIdx.x;
  const float* __restrict__ base = pred + (size_t)img * (NPRED * 8);

  // ---- phase A: score all anchors once; cache in LDS; histogram ----
  for (int b = tid; b < NBINS; b += NTHR) hist[b] = 0u;
  if (tid == 0) cnt_s = 0;
  __syncthreads();
  for (int e = tid; e < NPRED; e += NTHR) {
    const float4 q = *reinterpret_cast<const float4*>(base + (size_t)e * 8 + 4);
    float m = fmaxf(q.x * q.y, fmaxf(q.x * q.z, q.x * q.w));  // obj*cls, max
    scoreL[e] = m;
    int b = (int)(m * (float)NBINS);
    b = min(max(b, 0), NBINS - 1);
    atomicAdd(&hist[b], 1u);
  }
  __syncthreads();
  // coarse 4-bin sums + suffix scan
  gsum[tid] = hist[4 * tid] + hist[4 * tid + 1] + hist[4 * tid + 2] + hist[4 * tid + 3];
  __syncthreads();
  for (int d = 1; d < NTHR; d <<= 1) {
    unsigned v = gsum[tid] + ((tid + d < NTHR) ? gsum[tid + d] : 0u);
    __syncthreads();
    gsum[tid] = v;
    __syncthreads();
  }
  // cutoff = max bin b with suffix_count(b) >= KTOP (exactly one thread matches)
  if (gsum[tid] >= KTOP && (tid == NTHR - 1 || gsum[tid + 1] < KTOP)) {
    unsigned acc = (tid == NTHR - 1) ? 0u : gsum[tid + 1];
    int b = 4 * tid + 4;
    do { --b; acc += hist[b]; } while (acc < KTOP && b > 4 * tid);
    cutoff_s = b;
  }
  __syncthreads();
  const int cutoff = cutoff_s;

  // ---- phase B: collect candidates with bin >= cutoff (superset of top-K) ----
  for (int e = tid; e < NPRED; e += NTHR) {
    float v = scoreL[e];
    int b = (int)(v * (float)NBINS);
    b = min(max(b, 0), NBINS - 1);
    if (b >= cutoff) {
      int p = atomicAdd(&cnt_s, 1);
      if (p < CAP) { sv[p] = v; si[p] = e; }
    }
  }
  __syncthreads();
  {
    int cnt = min(cnt_s, CAP);
    if (tid >= cnt) { sv[tid] = -1e30f; si[tid] = 0x7fffffff; }
  }
  __syncthreads();

  // ---- phase C: bitonic sort CAP pairs, desc by value / asc by index ----
  for (int k = 2; k <= CAP; k <<= 1) {
    for (int j = k >> 1; j > 0; j >>= 1) {
      int ixj = tid ^ j;
      if (ixj > tid) {
        float va = sv[tid], vb = sv[ixj];
        int ia = si[tid], ib = si[ixj];
        bool aWorse = (va < vb) || (va == vb && ia > ib);
        bool up = ((tid & k) == 0);
        if (up == aWorse) {
          sv[tid] = vb; sv[ixj] = va;
          si[tid] = ib; si[ixj] = ia;
        }
      }
      __syncthreads();
    }
  }
  // phase-1 LDS region is dead from here; phase-2 views take over.

  // ---- phase D: build boxes for top-K ----
  if (tid < KTOP) {
    int gi = si[tid];
    const float4 a = *reinterpret_cast<const float4*>(base + (size_t)gi * 8);
    const float4 q = *reinterpret_cast<const float4*>(base + (size_t)gi * 8 + 4);
    float p0 = q.x * q.y, p1 = q.x * q.z, p2 = q.x * q.w;
    float m = fmaxf(p0, fmaxf(p1, p2));
    int c = (p0 == m) ? 0 : ((p1 == m) ? 1 : 2);   // first-max == jnp.argmax
    float x0 = a.x - a.z * 0.5f;
    float y0 = a.y - a.w * 0.5f;
    float x1 = a.x + a.z * 0.5f;
    float y1 = a.y + a.w * 0.5f;
    float co = (float)c * MAXWH;
    bx0[tid] = x0; bx1[tid] = y0; bx2[tid] = x1; bx3[tid] = y1;
    float o0 = x0 + co, o1 = y0 + co, o2 = x1 + co, o3 = y1 + co;
    ox0[tid] = o0; oy0[tid] = o1; ox1[tid] = o2; oy1[tid] = o3;
    areaL[tid] = (o2 - o0) * (o3 - o1);
    cidL[tid] = c;
  }
  __syncthreads();

  // ---- phase E: 512x512 suppression bitmask (i suppresses j>i if IoU>thr) ----
  for (int w = tid; w < KTOP * 16; w += NTHR) {
    int i = w & (KTOP - 1);
    int jw = w >> 9;                  // wave-uniform -> broadcast reads of [j]
    unsigned m = 0u;
    int jbase = jw << 5;
    if (jbase + 31 > i) {
      float ax0 = ox0[i], ay0 = oy0[i], ax1 = ox1[i], ay1 = oy1[i];
      float aa = areaL[i];
#pragma unroll
      for (int bb = 0; bb < 32; ++bb) {
        int j = jbase + bb;
        if (j > i) {
          float ix0 = fmaxf(ax0, ox0[j]);
          float iy0 = fmaxf(ay0, oy0[j]);
          float ix1 = fminf(ax1, ox1[j]);
          float iy1 = fminf(ay1, oy1[j]);
          float iw = fmaxf(ix1 - ix0, 0.0f);
          float ih = fmaxf(iy1 - iy0, 0.0f);
          float inter = iw * ih;
          float denom = aa + areaL[j] - inter + 1e-7f;
          if (inter > IOU_T * denom) m |= (1u << bb);
        }
      }
    }
    mask[i * 17 + jw] = m;
  }
  __syncthreads();

  // ---- phase F: greedy walk, register-chunked (16 lanes hold 512-bit state) ----
  // Chunks of 16 rows: preload each lane's mask column-word + the diagonal
  // word; the serial dependency becomes pure ALU (no per-step LDS/shfl).
  if (tid < 16) {
    unsigned s = 0u;
    const int lane = tid;
    for (int c = 0; c < KTOP / 16; ++c) {
      const int rb = c * 16;
      const int wi = rb >> 5;       // word holding this chunk's bits
      const int b0 = rb & 31;
      unsigned myrow[16], diag[16];
#pragma unroll
      for (int r = 0; r < 16; ++r) {
        myrow[r] = mask[(rb + r) * 17 + lane];
        diag[r]  = mask[(rb + r) * 17 + wi];
      }
      unsigned wcur = __shfl(s, wi, 64);   // word wi of current state
#pragma unroll
      for (int r = 0; r < 16; ++r) {
        if (!((wcur >> (b0 + r)) & 1u)) { s |= myrow[r]; wcur |= diag[r]; }
      }
    }
    supW[lane] = s;
  }
  __syncthreads();

  // ---- phase G: rank/valid + stable partition pack (== reference top_k) ----
  bool keep = false, valid = false;
  float score = 0.0f;
  if (tid < KTOP) {
    keep = !((supW[tid >> 5] >> (tid & 31)) & 1u);
    score = sv[tid];
    scanb[tid] = keep ? 1 : 0;
  }
  __syncthreads();
  for (int d = 1; d < KTOP; d <<= 1) {          // inclusive scan of keep -> rank
    int v = 0;
    if (tid < KTOP) { v = scanb[tid]; if (tid >= d) v += scanb[tid - d]; }
    __syncthreads();
    if (tid < KTOP) scanb[tid] = v;
    __syncthreads();
  }
  if (tid < KTOP) {
    int rank = scanb[tid];
    valid = keep && ((score > CONF_T) || (rank <= 1));  // MIN_DET = 1
  }
  __syncthreads();
  if (tid < KTOP) scanb[tid] = valid ? 1 : 0;
  __syncthreads();
  for (int d = 1; d < KTOP; d <<= 1) {          // inclusive scan of valid
    int v = 0;
    if (tid < KTOP) { v = scanb[tid]; if (tid >= d) v += scanb[tid - d]; }
    __syncthreads();
    if (tid < KTOP) scanb[tid] = v;
    __syncthreads();
  }
  if (tid < KTOP) {
    int vs = scanb[tid];
    int nvalid = scanb[KTOP - 1];
    // valid entries first (score order), then invalid entries (slot order)
    int pos = valid ? (vs - 1) : (nvalid + tid - vs);
    if (pos < MAXDET) {
      const int SB = BS * MAXDET;
      float* outBoxes  = out;                    // [BS][300][4]
      float* outScores = out + (size_t)SB * 4;   // [BS][300]
      float* outCls    = outScores + SB;
      float* outIds    = outCls + SB;
      float* outValid  = outIds + SB;
      size_t row = (size_t)img * MAXDET + pos;
      if (valid) {
        outBoxes[row * 4 + 0] = bx0[tid];
        outBoxes[row * 4 + 1] = bx1[tid];
        outBoxes[row * 4 + 2] = bx2[tid];
        outBoxes[row * 4 + 3] = bx3[tid];
        outScores[row] = score;
      } else {
        outBoxes[row * 4 + 0] = 0.0f;
        outBoxes[row * 4 + 1] = 0.0f;
        outBoxes[row * 4 + 2] = 0.0f;
        outBoxes[row * 4 + 3] = 0.0f;
        outScores[row] = 0.0f;
      }
      outCls[row]   = (float)cidL[tid];          // not masked (matches reference)
      outIds[row]   = (float)(si[tid] / 3);      // topi // ANCHORS_PER_CELL
      outValid[row] = valid ? 1.0f : 0.0f;
    }
  }
}

extern "C" void kernel_launch(void* const* d_in, const int* in_sizes, int n_in,
                              void* d_out, int out_size, void* d_ws, size_t ws_size,
                              hipStream_t stream) {
  (void)in_sizes; (void)n_in; (void)out_size; (void)d_ws; (void)ws_size;
  const float* pred = (const float*)d_in[0];
  float* out = (float*)d_out;
  yolo_k<<<BS, NTHR, 0, stream>>>(pred, out);
}